// Round 8
// baseline (522.116 us; speedup 1.0000x reference)
//
#include <hip/hip_runtime.h>
#include <math.h>

namespace {

typedef short short8 __attribute__((ext_vector_type(8)));
typedef int i32x4 __attribute__((ext_vector_type(4)));
typedef float f32x4 __attribute__((ext_vector_type(4)));

constexpr int kB = 4, kT = 2048, kD = 512, kE = 4, kC = 1024, kHE = 512,
              kO = 512, kEC = 4096;

__device__ __forceinline__ unsigned short f2bf(float f) {
    unsigned int u = __float_as_uint(f);
    u += 0x7fffu + ((u >> 16) & 1u);   // RNE
    return (unsigned short)(u >> 16);
}

__device__ __forceinline__ float gelu_exact(float v) {
    return 0.5f * v * (1.0f + erff(v * 0.70710678118654752f));
}

#define GLDS16(g, l)                                                      \
    __builtin_amdgcn_global_load_lds(                                     \
        (const __attribute__((address_space(1))) unsigned int*)(g),       \
        (__attribute__((address_space(3))) unsigned int*)(l), 16, 0, 0)

// ---------------------------------------------------------------------------
// Transpose+cast v2 (split launches — R5-proven): in[z] R x Cc fp32 ->
// out[z] Cc x R bf16. 64(r) x 32(c) tiles; both global phases 128 B per
// 32-lane group (fp32 reads; packed 2xbf16 uint stores).
__global__ __launch_bounds__(256)
void transpose_cast(const float* __restrict__ in, unsigned short* __restrict__ out,
                    int R, int Cc, long long sIn, long long sOut)
{
    __shared__ float tile[64][33];
    const int z = blockIdx.z;
    const float* ip = in + (long long)z * sIn;
    unsigned short* op = out + (long long)z * sOut;
    const int c0 = blockIdx.x * 32, r0 = blockIdx.y * 64;
    const int tx = threadIdx.x & 31, ty = threadIdx.x >> 5;  // ty 0..7
#pragma unroll
    for (int i = 0; i < 8; ++i) {
        const int r = ty + i * 8;
        tile[r][tx] = ip[(size_t)(r0 + r) * Cc + c0 + tx];
    }
    __syncthreads();
#pragma unroll
    for (int i = 0; i < 4; ++i) {
        const int c = ty + i * 8;
        const unsigned lo = f2bf(tile[tx * 2][c]);
        const unsigned hi = f2bf(tile[tx * 2 + 1][c]);
        *(unsigned*)&op[(size_t)(c0 + c) * R + r0 + tx * 2] = lo | (hi << 16);
    }
}

// Plain elementwise fp32 -> bf16 (n multiple of 4).
__global__ __launch_bounds__(256)
void cast_bf16(const float* __restrict__ in, unsigned short* __restrict__ out,
               long long n)
{
    const long long i = ((long long)blockIdx.x * blockDim.x + threadIdx.x) * 4;
    if (i < n) {
        const float4 v = *(const float4*)&in[i];
        unsigned short o[4] = {f2bf(v.x), f2bf(v.y), f2bf(v.z), f2bf(v.w)};
        *(uint2*)&out[i] = *(const uint2*)o;
    }
}

// ---------------------------------------------------------------------------
// MFMA GEMM — R3/R5-proven structure + wave-parity phase swap:
// C[z] = A[z%zModA] (MxK, k-contig) * B[z%zModB]^T (NxK, k-contig)
// B element (n,k) at ((k>>bShift)*N + n)<<bShift | (k & mask).
// MODE: 0 = bf16 store, 1 = bf16 store of gelu(acc+bias[n]), 3 = f32 acc+bias[n].
// 4 LDS buffers, depth-2 counted-vmcnt GLDS prefetch, fragment-level register
// double-buffer via inline-asm ds_read_b128. NEW: odd waves run
// READ16;MFMA16, even waves MFMA16;READ16 — de-lockstepping the 4 waves'
// DS-read bursts (the measured ~600-cyc lgkm tail came from all 4 waves
// queuing 16 b128 reads simultaneously; parity-split halves port queue
// depth so each wave's reads land within its MFMA shadow). T5 setprio
// around the MFMA cluster (waves now have role diversity per phase).
// T1 XCD swizzle, T2 XOR swizzle (bank conflicts == 0) retained.
template <int MODE>
__global__ __launch_bounds__(256, 1)
void mfma_gemm(const unsigned short* __restrict__ Aall,
               const unsigned short* __restrict__ Ball,
               const float* __restrict__ biasAll,
               void* __restrict__ Call,
               int M, int N, int K,
               long long sA, long long sB, long long sC,
               int zModA, int zModB, int zModBias, int biasStride, int bShift)
{
    __shared__ unsigned short As[4][128 * 64];
    __shared__ unsigned short Bs[4][128 * 64];

    const int z = blockIdx.z;
    const unsigned short* Ab = Aall + (long long)(z % zModA) * sA;
    const unsigned short* Bb = Ball + (long long)(z % zModB) * sB;
    const float* bias =
        (MODE != 0) ? biasAll + (long long)(z % zModBias) * biasStride : nullptr;

    // T1: XCD-aware remap of the (x,y) tile index (bijective when nwg%8==0).
    const int gx = gridDim.x;
    int lin = blockIdx.y * gx + blockIdx.x;
    const int nwg = gx * gridDim.y;
    if ((nwg & 7) == 0) {
        const int q = nwg >> 3;
        lin = (lin & 7) * q + (lin >> 3);
    }
    const int gxs = 31 - __clz(gx);          // gx is a power of 2 here
    const int bx = lin & (gx - 1);
    const int by = lin >> gxs;
    const int row0 = by * 128;
    const int colB = bx * 128;

    const int t = threadIdx.x;
    const int lane = t & 63;
    const int w = t >> 6;           // wave 0..3
    const int wrow = w * 32;        // staging row block per wave
    const int l8r = lane >> 3;      // 0..7  (row within 8-row staging group)
    // pre-swizzled global k offset: LDS slot (lane&7) holds global slot
    // ((lane&7) ^ (row&7)); row&7 == l8r for every staged row group.
    const int l8c = ((lane & 7) ^ l8r) * 8;

    const int wm = (w >> 1) * 64;   // wave's 64x64 quadrant
    const int wn = (w & 1) * 64;
    const int fr = lane & 15;       // fragment row/col within 16
    const int fq = (lane >> 4) * 8; // fragment k offset
    const int fsw = (fr & 7) * 8;   // read-side swizzle XOR (row&7 == fr&7)

    const unsigned int bMask = (1u << bShift) - 1u;

    f32x4 acc[4][4] = {};

    // LDS byte addresses for the asm ds_reads. kk=0 column = fq^fsw;
    // kk=1 column differs in element bit5 -> byte addr ^64.
    const unsigned aB0 =
        (unsigned)(size_t)(const __attribute__((address_space(3))) unsigned short*)
            &As[0][0] +
        (unsigned)(((wm + fr) * 64 + (fq ^ fsw)) * 2);
    const unsigned bB0 =
        (unsigned)(size_t)(const __attribute__((address_space(3))) unsigned short*)
            &Bs[0][0] +
        (unsigned)(((wn + fr) * 64 + (fq ^ fsw)) * 2);

    struct FragSet { i32x4 a0[4], a1[4], b0[4], b1[4]; };
    FragSet R0, R1;

    const bool rdFirst = (w & 1) != 0;   // wave-uniform

#define DSR0(d, a) asm volatile("ds_read_b128 %0, %1" : "=v"(d) : "v"(a))
#define DSR1(d, a) asm volatile("ds_read_b128 %0, %1 offset:2048" : "=v"(d) : "v"(a))
#define DSR2(d, a) asm volatile("ds_read_b128 %0, %1 offset:4096" : "=v"(d) : "v"(a))
#define DSR3(d, a) asm volatile("ds_read_b128 %0, %1 offset:6144" : "=v"(d) : "v"(a))

#define READ16(R, CB)                                                         \
    do {                                                                      \
        const unsigned A0c = aB0 + (CB) * 16384u, A1c = A0c ^ 64u;            \
        const unsigned B0c = bB0 + (CB) * 16384u, B1c = B0c ^ 64u;            \
        DSR0(R.a0[0], A0c); DSR1(R.a0[1], A0c); DSR2(R.a0[2], A0c); DSR3(R.a0[3], A0c); \
        DSR0(R.b0[0], B0c); DSR1(R.b0[1], B0c); DSR2(R.b0[2], B0c); DSR3(R.b0[3], B0c); \
        DSR0(R.a1[0], A1c); DSR1(R.a1[1], A1c); DSR2(R.a1[2], A1c); DSR3(R.a1[3], A1c); \
        DSR0(R.b1[0], B1c); DSR1(R.b1[1], B1c); DSR2(R.b1[2], B1c); DSR3(R.b1[3], B1c); \
    } while (0)

#define MFMA16(R)                                                             \
    do {                                                                      \
        _Pragma("unroll") for (int i_ = 0; i_ < 4; ++i_)                      \
            _Pragma("unroll") for (int j_ = 0; j_ < 4; ++j_)                  \
                acc[i_][j_] = __builtin_amdgcn_mfma_f32_16x16x32_bf16(        \
                    __builtin_bit_cast(short8, R.a0[i_]),                     \
                    __builtin_bit_cast(short8, R.b0[j_]), acc[i_][j_], 0, 0, 0); \
        _Pragma("unroll") for (int i_ = 0; i_ < 4; ++i_)                      \
            _Pragma("unroll") for (int j_ = 0; j_ < 4; ++j_)                  \
                acc[i_][j_] = __builtin_amdgcn_mfma_f32_16x16x32_bf16(        \
                    __builtin_bit_cast(short8, R.a1[i_]),                     \
                    __builtin_bit_cast(short8, R.b1[j_]), acc[i_][j_], 0, 0, 0); \
    } while (0)

#define STAGE(buf, k0)                                                        \
    do {                                                                      \
        _Pragma("unroll")                                                     \
        for (int r = 0; r < 4; ++r) {                                         \
            const int ar = row0 + wrow + r * 8 + l8r;                         \
            GLDS16(Ab + (size_t)ar * K + ((k0) + l8c),                        \
                   &As[buf][(wrow + r * 8) * 64]);                            \
            const int bn = colB + wrow + r * 8 + l8r;                         \
            const int gk = (k0) + l8c;                                        \
            const size_t boff =                                               \
                (((size_t)(gk >> bShift) * N + bn) << bShift) + (gk & bMask); \
            GLDS16(Bb + boff, &Bs[buf][(wrow + r * 8) * 64]);                 \
        }                                                                     \
    } while (0)

// Parity-phased step: odd waves READ then MFMA; even waves MFMA then READ.
// Both orders are data-safe: Rmf was read+drained last iter; Rrd's consumers
// are next iter (after this iter's lgkm(0)).
#define ITER_FULL(T, CBRD, CBST, Rmf, Rrd)                                    \
    do {                                                                      \
        STAGE(CBST, ((T) + 2) * 64);                                          \
        asm volatile("s_waitcnt vmcnt(8)" ::: "memory");                      \
        __builtin_amdgcn_s_barrier();                                         \
        if (rdFirst) {                                                        \
            READ16(Rrd, CBRD);                                                \
            __builtin_amdgcn_s_setprio(1);                                    \
            MFMA16(Rmf);                                                      \
            __builtin_amdgcn_s_setprio(0);                                    \
        } else {                                                              \
            __builtin_amdgcn_s_setprio(1);                                    \
            MFMA16(Rmf);                                                      \
            __builtin_amdgcn_s_setprio(0);                                    \
            READ16(Rrd, CBRD);                                                \
        }                                                                     \
        asm volatile("s_waitcnt lgkmcnt(0)" ::: "memory");                    \
        __builtin_amdgcn_sched_barrier(0);                                    \
    } while (0)

    const int nt = K / 64;   // 8, 32, or 64 here (always % 4 == 0, >= 8)

    // prologue: tiles 0,1 in flight; read tile-0 fragments into R0
    STAGE(0, 0);
    STAGE(1, 64);
    asm volatile("s_waitcnt vmcnt(8)" ::: "memory");
    __builtin_amdgcn_s_barrier();
    READ16(R0, 0);
    asm volatile("s_waitcnt lgkmcnt(0)" ::: "memory");
    __builtin_amdgcn_sched_barrier(0);

    for (int t0 = 0; t0 + 4 < nt; t0 += 4) {
        ITER_FULL(t0 + 0, 1, 2, R0, R1);
        ITER_FULL(t0 + 1, 2, 3, R1, R0);
        ITER_FULL(t0 + 2, 3, 0, R0, R1);
        ITER_FULL(t0 + 3, 0, 1, R1, R0);
    }
    // tail: t = nt-4 .. nt-1
    ITER_FULL(nt - 4, 1, 2, R0, R1);
    ITER_FULL(nt - 3, 2, 3, R1, R0);
    asm volatile("s_waitcnt vmcnt(0)" ::: "memory");
    __builtin_amdgcn_s_barrier();
    READ16(R1, 3);
    MFMA16(R0);
    asm volatile("s_waitcnt lgkmcnt(0)" ::: "memory");
    __builtin_amdgcn_sched_barrier(0);
    MFMA16(R1);

#undef ITER_FULL
#undef STAGE
#undef MFMA16
#undef READ16
#undef DSR0
#undef DSR1
#undef DSR2
#undef DSR3

    // Epilogue. C/D layout: col = lane&15, row = (lane>>4)*4 + reg  [m89/m91].
    const long long cz = (long long)z * sC;
#pragma unroll
    for (int i = 0; i < 4; ++i) {
        const int rowb = row0 + wm + i * 16 + (lane >> 4) * 4;
#pragma unroll
        for (int j = 0; j < 4; ++j) {
            const int col = colB + wn + j * 16 + fr;
            const float bv = (MODE != 0) ? bias[col] : 0.0f;
#pragma unroll
            for (int r = 0; r < 4; ++r) {
                const float v = acc[i][j][r];
                const size_t idx = (size_t)cz + (size_t)(rowb + r) * N + col;
                if (MODE == 0)
                    ((unsigned short*)Call)[idx] = f2bf(v);
                else if (MODE == 1)
                    ((unsigned short*)Call)[idx] = f2bf(gelu_exact(v + bv));
                else
                    ((float*)Call)[idx] = v + bv;
            }
        }
    }
}

}  // namespace

extern "C" void kernel_launch(void* const* d_in, const int* in_sizes, int n_in,
                              void* d_out, int out_size, void* d_ws, size_t ws_size,
                              hipStream_t stream)
{
    const float* x    = (const float*)d_in[0];  // (B,T,D)
    const float* mask = (const float*)d_in[1];  // (B,T,EC)
    const float* comb = (const float*)d_in[2];  // (B,T,EC)
    const float* w1   = (const float*)d_in[3];  // (E,D,HE)
    const float* b1   = (const float*)d_in[4];  // (E,HE)
    const float* w2   = (const float*)d_in[5];  // (E,HE,O)
    const float* b2   = (const float*)d_in[6];  // (O,)
    float* out = (float*)d_out;                 // (B,T,O) fp32

    // Workspace (bf16 elements): 108 MB total (R5-proven layout).
    unsigned short* ws    = (unsigned short*)d_ws;
    unsigned short* regA  = ws;                  // 33,554,432: maskT, then combB
    unsigned short* xT    = regA + 33554432;     //  4,194,304: [B][D][T]
    unsigned short* w1T   = xT + 4194304;        //  1,048,576: [E][HE][D]
    unsigned short* w2T   = w1T + 1048576;       //  1,048,576: [E][O][HE]
    unsigned short* xd    = w2T + 1048576;       //  8,388,608: [B][EC][D]; reused as yT
    unsigned short* h     = xd + 8388608;        //  8,388,608: [B*E][C][HE]
    unsigned short* maskT = regA;                // [B][EC][T]
    unsigned short* combB = regA;                // [B][T][EC]
    unsigned short* yT    = xd;

    dim3 blk(256);

    // --- conversions (v2 transpose, split launches — R5-proven) ---
    transpose_cast<<<dim3(kEC / 32, kT / 64, kB), blk, 0, stream>>>(
        mask, maskT, kT, kEC, (long long)kT * kEC, (long long)kT * kEC);
    transpose_cast<<<dim3(kD / 32, kT / 64, kB), blk, 0, stream>>>(
        x, xT, kT, kD, (long long)kT * kD, (long long)kT * kD);
    transpose_cast<<<dim3(kHE / 32, kD / 64, kE), blk, 0, stream>>>(
        w1, w1T, kD, kHE, (long long)kD * kHE, (long long)kD * kHE);
    transpose_cast<<<dim3(kO / 32, kHE / 64, kE), blk, 0, stream>>>(
        w2, w2T, kHE, kO, (long long)kHE * kO, (long long)kHE * kO);

    // --- stage 1: xd[b][ec][d] = sum_t maskT[b][ec][t] * xT[b][d][t] ---
    mfma_gemm<0><<<dim3(kD / 128, kEC / 128, kB), blk, 0, stream>>>(
        maskT, xT, nullptr, xd, kEC, kD, kT,
        (long long)kEC * kT, (long long)kD * kT, (long long)kEC * kD,
        kB, kB, 1, 0, 11);

    // comb cast (after stage 1 — reuses maskT's region, stream-ordered)
    cast_bf16<<<dim3(33554432 / 4 / 256), blk, 0, stream>>>(
        comb, combB, 33554432LL);

    // --- stage 2: h[g][c][he] = gelu(xd[g]*w1T[e]^T + b1[e]) ---
    mfma_gemm<1><<<dim3(kHE / 128, kC / 128, kB * kE), blk, 0, stream>>>(
        xd, w1T, b1, h, kC, kHE, kD,
        (long long)kC * kD, (long long)kHE * kD, (long long)kC * kHE,
        kB * kE, kE, kE, kHE, 9);

    // --- stage 3 (swapped): yT[g][o][c] = w2T[e]*h[g]^T ---
    mfma_gemm<0><<<dim3(kC / 128, kO / 128, kB * kE), blk, 0, stream>>>(
        w2T, h, nullptr, yT, kO, kC, kHE,
        (long long)kO * kHE, (long long)kC * kHE, (long long)kO * kC,
        kE, kB * kE, 1, 0, 9);

    // --- stage 4: out[b][t][o] = sum_ec combB[b][t][ec]*yT[b][e][o][c] + b2 ---
    mfma_gemm<3><<<dim3(kO / 128, kT / 128, kB), blk, 0, stream>>>(
        combB, yT, b2, out, kT, kO, kEC,
        (long long)kT * kEC, (long long)kE * kO * kC, (long long)kT * kO,
        kB, kB, 1, 0, 10);
}

// Round 9
// 424.812 us; speedup vs baseline: 1.2291x; 1.2291x over previous
//
#include <hip/hip_runtime.h>
#include <math.h>

namespace {

typedef short short8 __attribute__((ext_vector_type(8)));
typedef int i32x4 __attribute__((ext_vector_type(4)));
typedef float f32x4 __attribute__((ext_vector_type(4)));

constexpr int kB = 4, kT = 2048, kD = 512, kE = 4, kC = 1024, kHE = 512,
              kO = 512, kEC = 4096;

__device__ __forceinline__ unsigned short f2bf(float f) {
    unsigned int u = __float_as_uint(f);
    u += 0x7fffu + ((u >> 16) & 1u);   // RNE
    return (unsigned short)(u >> 16);
}

__device__ __forceinline__ float gelu_exact(float v) {
    return 0.5f * v * (1.0f + erff(v * 0.70710678118654752f));
}

#define GLDS16(g, l)                                                      \
    __builtin_amdgcn_global_load_lds(                                     \
        (const __attribute__((address_space(1))) unsigned int*)(g),       \
        (__attribute__((address_space(3))) unsigned int*)(l), 16, 0, 0)

// ---------------------------------------------------------------------------
// Transpose+cast v2 (split launches — R5-proven): in[z] R x Cc fp32 ->
// out[z] Cc x R bf16. 64(r) x 32(c) tiles; both global phases 128 B per
// 32-lane group (fp32 reads; packed 2xbf16 uint stores).
__global__ __launch_bounds__(256)
void transpose_cast(const float* __restrict__ in, unsigned short* __restrict__ out,
                    int R, int Cc, long long sIn, long long sOut)
{
    __shared__ float tile[64][33];
    const int z = blockIdx.z;
    const float* ip = in + (long long)z * sIn;
    unsigned short* op = out + (long long)z * sOut;
    const int c0 = blockIdx.x * 32, r0 = blockIdx.y * 64;
    const int tx = threadIdx.x & 31, ty = threadIdx.x >> 5;  // ty 0..7
#pragma unroll
    for (int i = 0; i < 8; ++i) {
        const int r = ty + i * 8;
        tile[r][tx] = ip[(size_t)(r0 + r) * Cc + c0 + tx];
    }
    __syncthreads();
#pragma unroll
    for (int i = 0; i < 4; ++i) {
        const int c = ty + i * 8;
        const unsigned lo = f2bf(tile[tx * 2][c]);
        const unsigned hi = f2bf(tile[tx * 2 + 1][c]);
        *(unsigned*)&op[(size_t)(c0 + c) * R + r0 + tx * 2] = lo | (hi << 16);
    }
}

// Plain elementwise fp32 -> bf16 (n multiple of 4).
__global__ __launch_bounds__(256)
void cast_bf16(const float* __restrict__ in, unsigned short* __restrict__ out,
               long long n)
{
    const long long i = ((long long)blockIdx.x * blockDim.x + threadIdx.x) * 4;
    if (i < n) {
        const float4 v = *(const float4*)&in[i];
        unsigned short o[4] = {f2bf(v.x), f2bf(v.y), f2bf(v.z), f2bf(v.w)};
        *(uint2*)&out[i] = *(const uint2*)o;
    }
}

// ---------------------------------------------------------------------------
// MFMA GEMM — R3 structure at NB=2 (64 KB LDS) for 2 blocks/CU:
// C[z] = A[z%zModA] (MxK, k-contig) * B[z%zModB]^T (NxK, k-contig)
// B element (n,k) at ((k>>bShift)*N + n)<<bShift | (k & mask).
// MODE: 0 = bf16 store, 1 = bf16 store of gelu(acc+bias[n]), 3 = f32 acc+bias[n].
//
// Rationale: at 128 KB LDS only ONE block fits per CU (1 wave/SIMD, zero
// TLP) — every wait was on the critical path, and three rounds of
// compile-time rescheduling (fine interleave R5, depth-3 R4, parity R8)
// were null-to-negative. NB=2 halves LDS so TWO blocks co-reside
// (2 waves/SIMD); the co-resident block's waves hide the vmcnt drain and
// post-MFMA lgkm tail in hardware (m114 overlap).
// NB=2 hazard ledger (re-derived): STAGE(T+2) targets buf[T%2], which was
// read (tile T fragments) at iter T-1 and drained by every wave's lgkm(0)
// BEFORE barrier(T) -> STAGE must be issued AFTER the barrier. At iter-T
// entry only tile T+1's 8 loads are outstanding -> vmcnt(0) (issued a full
// step earlier; near-complete). Reg-fragment double-buffer (inline-asm
// ds_read_b128, monolithic READ16;MFMA16) retained verbatim from R3.
// T1 XCD swizzle, T2 XOR swizzle (bank conflicts == 0) retained.
template <int MODE>
__global__ __launch_bounds__(256, 2)
void mfma_gemm(const unsigned short* __restrict__ Aall,
               const unsigned short* __restrict__ Ball,
               const float* __restrict__ biasAll,
               void* __restrict__ Call,
               int M, int N, int K,
               long long sA, long long sB, long long sC,
               int zModA, int zModB, int zModBias, int biasStride, int bShift)
{
    __shared__ unsigned short As[2][128 * 64];
    __shared__ unsigned short Bs[2][128 * 64];

    const int z = blockIdx.z;
    const unsigned short* Ab = Aall + (long long)(z % zModA) * sA;
    const unsigned short* Bb = Ball + (long long)(z % zModB) * sB;
    const float* bias =
        (MODE != 0) ? biasAll + (long long)(z % zModBias) * biasStride : nullptr;

    // T1: XCD-aware remap of the (x,y) tile index (bijective when nwg%8==0).
    const int gx = gridDim.x;
    int lin = blockIdx.y * gx + blockIdx.x;
    const int nwg = gx * gridDim.y;
    if ((nwg & 7) == 0) {
        const int q = nwg >> 3;
        lin = (lin & 7) * q + (lin >> 3);
    }
    const int gxs = 31 - __clz(gx);          // gx is a power of 2 here
    const int bx = lin & (gx - 1);
    const int by = lin >> gxs;
    const int row0 = by * 128;
    const int colB = bx * 128;

    const int t = threadIdx.x;
    const int lane = t & 63;
    const int w = t >> 6;           // wave 0..3
    const int wrow = w * 32;        // staging row block per wave
    const int l8r = lane >> 3;      // 0..7  (row within 8-row staging group)
    // pre-swizzled global k offset: LDS slot (lane&7) holds global slot
    // ((lane&7) ^ (row&7)); row&7 == l8r for every staged row group.
    const int l8c = ((lane & 7) ^ l8r) * 8;

    const int wm = (w >> 1) * 64;   // wave's 64x64 quadrant
    const int wn = (w & 1) * 64;
    const int fr = lane & 15;       // fragment row/col within 16
    const int fq = (lane >> 4) * 8; // fragment k offset
    const int fsw = (fr & 7) * 8;   // read-side swizzle XOR (row&7 == fr&7)

    const unsigned int bMask = (1u << bShift) - 1u;

    f32x4 acc[4][4] = {};

    // LDS byte addresses for the asm ds_reads. kk=0 column = fq^fsw;
    // kk=1 column differs in element bit5 -> byte addr ^64.
    const unsigned aB0 =
        (unsigned)(size_t)(const __attribute__((address_space(3))) unsigned short*)
            &As[0][0] +
        (unsigned)(((wm + fr) * 64 + (fq ^ fsw)) * 2);
    const unsigned bB0 =
        (unsigned)(size_t)(const __attribute__((address_space(3))) unsigned short*)
            &Bs[0][0] +
        (unsigned)(((wn + fr) * 64 + (fq ^ fsw)) * 2);

    struct FragSet { i32x4 a0[4], a1[4], b0[4], b1[4]; };
    FragSet R0, R1;

#define DSR0(d, a) asm volatile("ds_read_b128 %0, %1" : "=v"(d) : "v"(a))
#define DSR1(d, a) asm volatile("ds_read_b128 %0, %1 offset:2048" : "=v"(d) : "v"(a))
#define DSR2(d, a) asm volatile("ds_read_b128 %0, %1 offset:4096" : "=v"(d) : "v"(a))
#define DSR3(d, a) asm volatile("ds_read_b128 %0, %1 offset:6144" : "=v"(d) : "v"(a))

#define READ16(R, CB)                                                         \
    do {                                                                      \
        const unsigned A0c = aB0 + (CB) * 16384u, A1c = A0c ^ 64u;            \
        const unsigned B0c = bB0 + (CB) * 16384u, B1c = B0c ^ 64u;            \
        DSR0(R.a0[0], A0c); DSR1(R.a0[1], A0c); DSR2(R.a0[2], A0c); DSR3(R.a0[3], A0c); \
        DSR0(R.b0[0], B0c); DSR1(R.b0[1], B0c); DSR2(R.b0[2], B0c); DSR3(R.b0[3], B0c); \
        DSR0(R.a1[0], A1c); DSR1(R.a1[1], A1c); DSR2(R.a1[2], A1c); DSR3(R.a1[3], A1c); \
        DSR0(R.b1[0], B1c); DSR1(R.b1[1], B1c); DSR2(R.b1[2], B1c); DSR3(R.b1[3], B1c); \
    } while (0)

#define MFMA16(R)                                                             \
    do {                                                                      \
        _Pragma("unroll") for (int i_ = 0; i_ < 4; ++i_)                      \
            _Pragma("unroll") for (int j_ = 0; j_ < 4; ++j_)                  \
                acc[i_][j_] = __builtin_amdgcn_mfma_f32_16x16x32_bf16(        \
                    __builtin_bit_cast(short8, R.a0[i_]),                     \
                    __builtin_bit_cast(short8, R.b0[j_]), acc[i_][j_], 0, 0, 0); \
        _Pragma("unroll") for (int i_ = 0; i_ < 4; ++i_)                      \
            _Pragma("unroll") for (int j_ = 0; j_ < 4; ++j_)                  \
                acc[i_][j_] = __builtin_amdgcn_mfma_f32_16x16x32_bf16(        \
                    __builtin_bit_cast(short8, R.a1[i_]),                     \
                    __builtin_bit_cast(short8, R.b1[j_]), acc[i_][j_], 0, 0, 0); \
    } while (0)

#define STAGE(buf, k0)                                                        \
    do {                                                                      \
        _Pragma("unroll")                                                     \
        for (int r = 0; r < 4; ++r) {                                         \
            const int ar = row0 + wrow + r * 8 + l8r;                         \
            GLDS16(Ab + (size_t)ar * K + ((k0) + l8c),                        \
                   &As[buf][(wrow + r * 8) * 64]);                            \
            const int bn = colB + wrow + r * 8 + l8r;                         \
            const int gk = (k0) + l8c;                                        \
            const size_t boff =                                               \
                (((size_t)(gk >> bShift) * N + bn) << bShift) + (gk & bMask); \
            GLDS16(Bb + boff, &Bs[buf][(wrow + r * 8) * 64]);                 \
        }                                                                     \
    } while (0)

// NB=2 step: drain tile T+1's loads; barrier (all waves' reads of buf[T%2]
// drained); stage tile T+2 into buf[T%2]; read tile T+1 fragments; MFMA
// tile T; drain own ds_reads.
#define ITER_FULL(T, Rmf, Rrd)                                                \
    do {                                                                      \
        asm volatile("s_waitcnt vmcnt(0)" ::: "memory");                      \
        __builtin_amdgcn_s_barrier();                                         \
        STAGE((T) & 1, ((T) + 2) * 64);                                       \
        READ16(Rrd, ((T) + 1) & 1);                                           \
        MFMA16(Rmf);                                                          \
        asm volatile("s_waitcnt lgkmcnt(0)" ::: "memory");                    \
        __builtin_amdgcn_sched_barrier(0);                                    \
    } while (0)

    const int nt = K / 64;   // 8, 32, or 64 here (always even, >= 8)

    // prologue: tiles 0,1 in flight; read tile-0 fragments into R0
    STAGE(0, 0);
    STAGE(1, 64);
    asm volatile("s_waitcnt vmcnt(8)" ::: "memory");
    __builtin_amdgcn_s_barrier();
    READ16(R0, 0);
    asm volatile("s_waitcnt lgkmcnt(0)" ::: "memory");
    __builtin_amdgcn_sched_barrier(0);

    for (int t0 = 0; t0 < nt - 2; t0 += 2) {
        ITER_FULL(t0 + 0, R0, R1);
        ITER_FULL(t0 + 1, R1, R0);
    }
    // tail: T = nt-2 (even -> Rmf = R0), no further staging
    asm volatile("s_waitcnt vmcnt(0)" ::: "memory");
    __builtin_amdgcn_s_barrier();
    READ16(R1, (nt - 1) & 1);
    MFMA16(R0);
    asm volatile("s_waitcnt lgkmcnt(0)" ::: "memory");
    __builtin_amdgcn_sched_barrier(0);
    // T = nt-1
    MFMA16(R1);

#undef ITER_FULL
#undef STAGE
#undef MFMA16
#undef READ16
#undef DSR0
#undef DSR1
#undef DSR2
#undef DSR3

    // Epilogue. C/D layout: col = lane&15, row = (lane>>4)*4 + reg  [m89/m91].
    const long long cz = (long long)z * sC;
#pragma unroll
    for (int i = 0; i < 4; ++i) {
        const int rowb = row0 + wm + i * 16 + (lane >> 4) * 4;
#pragma unroll
        for (int j = 0; j < 4; ++j) {
            const int col = colB + wn + j * 16 + fr;
            const float bv = (MODE != 0) ? bias[col] : 0.0f;
#pragma unroll
            for (int r = 0; r < 4; ++r) {
                const float v = acc[i][j][r];
                const size_t idx = (size_t)cz + (size_t)(rowb + r) * N + col;
                if (MODE == 0)
                    ((unsigned short*)Call)[idx] = f2bf(v);
                else if (MODE == 1)
                    ((unsigned short*)Call)[idx] = f2bf(gelu_exact(v + bv));
                else
                    ((float*)Call)[idx] = v + bv;
            }
        }
    }
}

}  // namespace

extern "C" void kernel_launch(void* const* d_in, const int* in_sizes, int n_in,
                              void* d_out, int out_size, void* d_ws, size_t ws_size,
                              hipStream_t stream)
{
    const float* x    = (const float*)d_in[0];  // (B,T,D)
    const float* mask = (const float*)d_in[1];  // (B,T,EC)
    const float* comb = (const float*)d_in[2];  // (B,T,EC)
    const float* w1   = (const float*)d_in[3];  // (E,D,HE)
    const float* b1   = (const float*)d_in[4];  // (E,HE)
    const float* w2   = (const float*)d_in[5];  // (E,HE,O)
    const float* b2   = (const float*)d_in[6];  // (O,)
    float* out = (float*)d_out;                 // (B,T,O) fp32

    // Workspace (bf16 elements): 108 MB total (R5-proven layout).
    unsigned short* ws    = (unsigned short*)d_ws;
    unsigned short* regA  = ws;                  // 33,554,432: maskT, then combB
    unsigned short* xT    = regA + 33554432;     //  4,194,304: [B][D][T]
    unsigned short* w1T   = xT + 4194304;        //  1,048,576: [E][HE][D]
    unsigned short* w2T   = w1T + 1048576;       //  1,048,576: [E][O][HE]
    unsigned short* xd    = w2T + 1048576;       //  8,388,608: [B][EC][D]; reused as yT
    unsigned short* h     = xd + 8388608;        //  8,388,608: [B*E][C][HE]
    unsigned short* maskT = regA;                // [B][EC][T]
    unsigned short* combB = regA;                // [B][T][EC]
    unsigned short* yT    = xd;

    dim3 blk(256);

    // --- conversions (v2 transpose, split launches — R5-proven) ---
    transpose_cast<<<dim3(kEC / 32, kT / 64, kB), blk, 0, stream>>>(
        mask, maskT, kT, kEC, (long long)kT * kEC, (long long)kT * kEC);
    transpose_cast<<<dim3(kD / 32, kT / 64, kB), blk, 0, stream>>>(
        x, xT, kT, kD, (long long)kT * kD, (long long)kT * kD);
    transpose_cast<<<dim3(kHE / 32, kD / 64, kE), blk, 0, stream>>>(
        w1, w1T, kD, kHE, (long long)kD * kHE, (long long)kD * kHE);
    transpose_cast<<<dim3(kO / 32, kHE / 64, kE), blk, 0, stream>>>(
        w2, w2T, kHE, kO, (long long)kHE * kO, (long long)kHE * kO);

    // --- stage 1: xd[b][ec][d] = sum_t maskT[b][ec][t] * xT[b][d][t] ---
    mfma_gemm<0><<<dim3(kD / 128, kEC / 128, kB), blk, 0, stream>>>(
        maskT, xT, nullptr, xd, kEC, kD, kT,
        (long long)kEC * kT, (long long)kD * kT, (long long)kEC * kD,
        kB, kB, 1, 0, 11);

    // comb cast (after stage 1 — reuses maskT's region, stream-ordered)
    cast_bf16<<<dim3(33554432 / 4 / 256), blk, 0, stream>>>(
        comb, combB, 33554432LL);

    // --- stage 2: h[g][c][he] = gelu(xd[g]*w1T[e]^T + b1[e]) ---
    mfma_gemm<1><<<dim3(kHE / 128, kC / 128, kB * kE), blk, 0, stream>>>(
        xd, w1T, b1, h, kC, kHE, kD,
        (long long)kC * kD, (long long)kHE * kD, (long long)kC * kHE,
        kB * kE, kE, kE, kHE, 9);

    // --- stage 3 (swapped): yT[g][o][c] = w2T[e]*h[g]^T ---
    mfma_gemm<0><<<dim3(kC / 128, kO / 128, kB * kE), blk, 0, stream>>>(
        w2T, h, nullptr, yT, kO, kC, kHE,
        (long long)kO * kHE, (long long)kC * kHE, (long long)kO * kC,
        kE, kB * kE, 1, 0, 9);

    // --- stage 4: out[b][t][o] = sum_ec combB[b][t][ec]*yT[b][e][o][c] + b2 ---
    mfma_gemm<3><<<dim3(kO / 128, kT / 128, kB), blk, 0, stream>>>(
        combB, yT, b2, out, kT, kO, kEC,
        (long long)kT * kEC, (long long)kE * kO * kC, (long long)kT * kO,
        kB, kB, 1, 0, 10);
}